// Round 7
// baseline (283.091 us; speedup 1.0000x reference)
//
#include <hip/hip_runtime.h>
#include <hip/hip_bf16.h>

#define EMBED 768
#define SEQ 2048
#define BATCH 8
#define ROWB 1536                 // bytes per bf16 row
#define KSPLIT 4
#define KCH (SEQ / KSPLIT)        // 512 keys per block
#define NKT (KCH / 32)            // 16 k-tiles of 32 keys
#define QBLK 128                  // q rows per block
#define QROWS 32                  // q rows per wave
#define HFRB (24 * 1024)          // half-tile: 24 fragments x 1024 B
#define V2OFF (2 * HFRB)          // v2 slots after the two half buffers
#define LDSZ (2 * HFRB + 512)     // 49664 B -> 2 blocks/CU

typedef __bf16 bf16x8 __attribute__((ext_vector_type(8)));
typedef float f32x4 __attribute__((ext_vector_type(4)));
typedef float f32x16 __attribute__((ext_vector_type(16)));

// ---------------- prep: x -> bf16, v2 = x @ W^T (fp32) ----------------
__global__ __launch_bounds__(256)
void prep_kernel(const float* __restrict__ x, const float* __restrict__ W,
                 __hip_bfloat16* __restrict__ xb, float* __restrict__ v2) {
  const int wave = threadIdx.x >> 6, lane = threadIdx.x & 63;
  const int row = blockIdx.x * 4 + wave;           // one wave per row
  const float* xr = x + (size_t)row * EMBED;
  float a0 = 0.f, a1 = 0.f;
#pragma unroll
  for (int j = 0; j < 3; ++j) {
    const int d = j * 256 + lane * 4;
    float4 v  = *(const float4*)(xr + d);
    float4 w0 = *(const float4*)(W + d);
    float4 w1 = *(const float4*)(W + EMBED + d);
    a0 += v.x * w0.x + v.y * w0.y + v.z * w0.z + v.w * w0.w;
    a1 += v.x * w1.x + v.y * w1.y + v.z * w1.z + v.w * w1.w;
    union { __hip_bfloat16 h[4]; uint2 u; } pk;
    pk.h[0] = __float2bfloat16(v.x);
    pk.h[1] = __float2bfloat16(v.y);
    pk.h[2] = __float2bfloat16(v.z);
    pk.h[3] = __float2bfloat16(v.w);
    *(uint2*)(xb + (size_t)row * EMBED + d) = pk.u;
  }
#pragma unroll
  for (int off = 1; off < 64; off <<= 1) {
    a0 += __shfl_xor(a0, off);
    a1 += __shfl_xor(a1, off);
  }
  if (lane == 0) {
    v2[row * 2 + 0] = a0;
    v2[row * 2 + 1] = a1;
  }
}

// ---- flash attention: S^T = mfma(K, Q), 32 q-rows/wave, half-tile ping-pong ----
// grid: blk = b + 8*ks + 32*qt  (b in [0,8) -> XCD, ks in [0,4), qt in [0,16))
__global__ __launch_bounds__(256, 2)
void attn_kernel(const __hip_bfloat16* __restrict__ xb, const float* __restrict__ v2,
                 float* __restrict__ part) {
  __shared__ char lds[LDSZ];
  const int tid = threadIdx.x;
  const int w = tid >> 6, l = tid & 63;
  const int lo = l & 31, hi = l >> 5;
  const int blk = blockIdx.x;
  const int b = blk & 7, ks = (blk >> 3) & 3, qt = blk >> 5;
  const int q0 = qt * QBLK + w * QROWS;

  const char* xbB = (const char*)xb + (size_t)b * SEQ * ROWB;

  // Q as MFMA B-operand: lane holds q-col (q0+lo), frag f covers dims f*16+hi*8+[0..7]
  bf16x8 qf[48];
  {
    const char* qr = xbB + (size_t)(q0 + lo) * ROWB + hi * 16;
#pragma unroll
    for (int f = 0; f < 48; ++f) qf[f] = *(const bf16x8*)(qr + f * 32);
  }
#pragma unroll
  for (int f = 0; f < 48; ++f) asm volatile("" :: "v"(qf[f]));

  // staging bases: wave w stages frags f = 24h + 6w + i, i in [0,6)
  const char* sW = xbB + (size_t)ks * KCH * ROWB + (size_t)lo * ROWB
                 + hi * 16 + w * 6 * 32;
  const char* v2s = (const char*)v2 + ((size_t)b * SEQ + ks * KCH) * 8 + l * 4;

  // stage half h of tile kt into buffer p (24 KB); optionally v2 tile kt2
#define STAGEH(p, kt, h)                                                         \
  do {                                                                           \
    const char* _s = sW + (size_t)(kt) * (32 * ROWB) + (h) * 24 * 32;            \
    char* _d = (char*)lds + (p) * HFRB + w * 6 * 1024 + l * 16;                  \
    _Pragma("unroll")                                                            \
    for (int _i = 0; _i < 6; ++_i)                                               \
      __builtin_amdgcn_global_load_lds(                                          \
          (const __attribute__((address_space(1))) void*)(_s + _i * 32),         \
          (__attribute__((address_space(3))) void*)(_d + _i * 1024), 16, 0, 0);  \
  } while (0)
#define STAGEV2(kt)                                                              \
  do {                                                                           \
    if (w == 0)                                                                  \
      __builtin_amdgcn_global_load_lds(                                          \
          (const __attribute__((address_space(1))) void*)(v2s + (kt) * 256),     \
          (__attribute__((address_space(3))) void*)((char*)lds + V2OFF + ((kt) & 1) * 256 + l * 4), \
          4, 0, 0);                                                              \
  } while (0)

  const float SC2 = 0.03608439182435161f * 1.44269504088896f;  // (1/sqrt(768))*log2e
  const float MB2 = 57.7078016355585f;                         // 40*log2e fixed max

  float ls = 0.f, c0 = 0.f, c1 = 0.f;    // per-lane: one q-row, half the keys

  STAGEH(0, 0, 0);
  STAGEV2(0);
  __syncthreads();

  f32x16 a0, a1;
  for (int kt = 0; kt < NKT; ++kt) {
    // ---- step A: compute dims 0..383 from buf0; stage dims 384..767 -> buf1
    STAGEH(1, kt, 1);
#pragma unroll
    for (int i = 0; i < 16; ++i) { a0[i] = 0.f; a1[i] = 0.f; }
    {
      const char* base = (const char*)lds + l * 16;
#pragma unroll
      for (int i = 0; i < 24; ++i) {
        bf16x8 kf = *(const bf16x8*)(base + i * 1024);
        if (i & 1) a1 = __builtin_amdgcn_mfma_f32_32x32x16_bf16(kf, qf[i], a1, 0, 0, 0);
        else       a0 = __builtin_amdgcn_mfma_f32_32x32x16_bf16(kf, qf[i], a0, 0, 0, 0);
      }
    }
    __syncthreads();

    // ---- step B: compute dims 384..767 from buf1; stage next tile half0 -> buf0
    if (kt + 1 < NKT) { STAGEH(0, kt + 1, 0); STAGEV2(kt + 1); }
    {
      const char* base = (const char*)lds + HFRB + l * 16;
#pragma unroll
      for (int i = 0; i < 24; ++i) {
        bf16x8 kf = *(const bf16x8*)(base + i * 1024);
        if (i & 1) a1 = __builtin_amdgcn_mfma_f32_32x32x16_bf16(kf, qf[24 + i], a1, 0, 0, 0);
        else       a0 = __builtin_amdgcn_mfma_f32_32x32x16_bf16(kf, qf[24 + i], a0, 0, 0, 0);
      }
    }
    // ---- softmax accumulate for tile kt (C: key=(r&3)+8*(r>>2)+4*hi, q-col=lo)
    {
      const char* vb = (const char*)lds + V2OFF + (kt & 1) * 256 + hi * 32;
#pragma unroll
      for (int rq = 0; rq < 4; ++rq) {
        f32x4 va = *(const f32x4*)(vb + rq * 64);        // keys 8rq+4hi, +1
        f32x4 vc = *(const f32x4*)(vb + rq * 64 + 16);   // keys 8rq+4hi+2, +3
#pragma unroll
        for (int j = 0; j < 4; ++j) {
          const float v0j = (j == 0) ? va[0] : (j == 1) ? va[2] : (j == 2) ? vc[0] : vc[2];
          const float v1j = (j == 0) ? va[1] : (j == 1) ? va[3] : (j == 2) ? vc[1] : vc[3];
          const int r = rq * 4 + j;
          const float p = exp2f(fmaf(a0[r] + a1[r], SC2, -MB2));
          ls += p; c0 = fmaf(p, v0j, c0); c1 = fmaf(p, v1j, c1);
        }
      }
    }
    __syncthreads();
  }
#undef STAGEH
#undef STAGEV2

  // fold the two hi-halves (same q-col, disjoint keys)
  ls += __shfl_xor(ls, 32); c0 += __shfl_xor(c0, 32); c1 += __shfl_xor(c1, 32);

  if (hi == 0) {
    float4* pp = (float4*)part + (size_t)ks * (BATCH * SEQ) + (size_t)b * SEQ;
    pp[q0 + lo] = make_float4(ls, c0, c1, 0.f);
  }
}

// ---------------- combine the 4 K-split partials + bias ----------------
__global__ __launch_bounds__(256)
void combine_kernel(const float* __restrict__ part, const float* __restrict__ bias,
                    float* __restrict__ out) {
  const int t = blockIdx.x * 256 + threadIdx.x;
  const float4* p4 = (const float4*)part;
  const float4 s0 = p4[t];
  const float4 s1 = p4[BATCH * SEQ + t];
  const float4 s2 = p4[2 * BATCH * SEQ + t];
  const float4 s3 = p4[3 * BATCH * SEQ + t];
  const float lsum = s0.x + s1.x + s2.x + s3.x;
  const float c0 = s0.y + s1.y + s2.y + s3.y;
  const float c1 = s0.z + s1.z + s2.z + s3.z;
  const float inv = 1.f / lsum;
  ((float2*)out)[t] = make_float2(c0 * inv + bias[0], c1 * inv + bias[1]);
}

extern "C" void kernel_launch(void* const* d_in, const int* in_sizes, int n_in,
                              void* d_out, int out_size, void* d_ws, size_t ws_size,
                              hipStream_t stream) {
  const float* x    = (const float*)d_in[0];
  const float* W    = (const float*)d_in[1];
  const float* bias = (const float*)d_in[2];
  float* out = (float*)d_out;

  __hip_bfloat16* xb = (__hip_bfloat16*)d_ws;                    // 25,165,824 B
  float* v2   = (float*)((char*)d_ws + 25165824);                //    131,072 B
  float* part = (float*)((char*)d_ws + 25165824 + 131072);       //  1,048,576 B

  prep_kernel<<<BATCH * SEQ / 4, 256, 0, stream>>>(x, W, xb, v2);
  attn_kernel<<<BATCH * KSPLIT * (SEQ / QBLK), 256, 0, stream>>>(xb, v2, part);
  combine_kernel<<<BATCH * SEQ / 256, 256, 0, stream>>>(part, bias, out);
}

// Round 13
// 174.902 us; speedup vs baseline: 1.6186x; 1.6186x over previous
//
#include <hip/hip_runtime.h>
#include <hip/hip_bf16.h>

#define EMBED 768
#define SEQ 2048
#define BATCH 8
#define ROWB 1536                 // bytes per bf16 row
#define KSPLIT 4
#define KCH (SEQ / KSPLIT)        // 512 keys per block
#define NKT (KCH / 32)            // 16 k-tiles of 32 keys
#define QBLK 128                  // q rows per block
#define QROWS 32                  // q rows per wave
#define HFRB (24 * 1024)          // half-tile: 24 fragments x 1024 B
#define V2OFF (2 * HFRB)          // v2 slots after the two half buffers
#define LDSZ (2 * HFRB + 512)     // 49664 B; VGPR<=256 -> 2 blocks/CU

typedef __bf16 bf16x8 __attribute__((ext_vector_type(8)));
typedef float f32x4 __attribute__((ext_vector_type(4)));
typedef float f32x16 __attribute__((ext_vector_type(16)));

// ---------------- prep: x -> bf16, v2 = x @ W^T (fp32) ----------------
__global__ __launch_bounds__(256)
void prep_kernel(const float* __restrict__ x, const float* __restrict__ W,
                 __hip_bfloat16* __restrict__ xb, float* __restrict__ v2) {
  const int wave = threadIdx.x >> 6, lane = threadIdx.x & 63;
  const int row = blockIdx.x * 4 + wave;           // one wave per row
  const float* xr = x + (size_t)row * EMBED;
  float a0 = 0.f, a1 = 0.f;
#pragma unroll
  for (int j = 0; j < 3; ++j) {
    const int d = j * 256 + lane * 4;
    float4 v  = *(const float4*)(xr + d);
    float4 w0 = *(const float4*)(W + d);
    float4 w1 = *(const float4*)(W + EMBED + d);
    a0 += v.x * w0.x + v.y * w0.y + v.z * w0.z + v.w * w0.w;
    a1 += v.x * w1.x + v.y * w1.y + v.z * w1.z + v.w * w1.w;
    union { __hip_bfloat16 h[4]; uint2 u; } pk;
    pk.h[0] = __float2bfloat16(v.x);
    pk.h[1] = __float2bfloat16(v.y);
    pk.h[2] = __float2bfloat16(v.z);
    pk.h[3] = __float2bfloat16(v.w);
    *(uint2*)(xb + (size_t)row * EMBED + d) = pk.u;
  }
#pragma unroll
  for (int off = 1; off < 64; off <<= 1) {
    a0 += __shfl_xor(a0, off);
    a1 += __shfl_xor(a1, off);
  }
  if (lane == 0) {
    v2[row * 2 + 0] = a0;
    v2[row * 2 + 1] = a1;
  }
}

// ---- flash attention: S^T = mfma(K, Q), 32 q-rows/wave, half-tile ping-pong ----
// grid: blk = b + 8*ks + 32*qt  (b in [0,8) -> XCD, ks in [0,4), qt in [0,16))
// NOTE: __launch_bounds__(256,1): under (256,2) the allocator spilled the whole
// 192-VGPR Q array (round 7: VGPR=128, 336 MB scratch traffic). With (256,1) it
// lands ~240 (round 4) and the HW still co-schedules 2 blocks/CU since 240<=256.
__global__ __launch_bounds__(256, 1)
void attn_kernel(const __hip_bfloat16* __restrict__ xb, const float* __restrict__ v2,
                 float* __restrict__ part) {
  __shared__ char lds[LDSZ];
  const int tid = threadIdx.x;
  const int w = tid >> 6, l = tid & 63;
  const int lo = l & 31, hi = l >> 5;
  const int blk = blockIdx.x;
  const int b = blk & 7, ks = (blk >> 3) & 3, qt = blk >> 5;
  const int q0 = qt * QBLK + w * QROWS;

  const char* xbB = (const char*)xb + (size_t)b * SEQ * ROWB;

  // Q as MFMA B-operand: lane holds q-col (q0+lo), frag f covers dims f*16+hi*8+[0..7]
  bf16x8 qf[48];
  {
    const char* qr = xbB + (size_t)(q0 + lo) * ROWB + hi * 16;
#pragma unroll
    for (int f = 0; f < 48; ++f) qf[f] = *(const bf16x8*)(qr + f * 32);
  }
#pragma unroll
  for (int f = 0; f < 48; ++f) asm volatile("" :: "v"(qf[f]));

  // staging bases: wave w stages frags f = 24h + 6w + i, i in [0,6)
  const char* sW = xbB + (size_t)ks * KCH * ROWB + (size_t)lo * ROWB
                 + hi * 16 + w * 6 * 32;
  const char* v2s = (const char*)v2 + ((size_t)b * SEQ + ks * KCH) * 8 + l * 4;

  // stage half h of tile kt into buffer p (24 KB); v2 tile into slot kt&1
#define STAGEH(p, kt, h)                                                         \
  do {                                                                           \
    const char* _s = sW + (size_t)(kt) * (32 * ROWB) + (h) * 24 * 32;            \
    char* _d = (char*)lds + (p) * HFRB + w * 6 * 1024 + l * 16;                  \
    _Pragma("unroll")                                                            \
    for (int _i = 0; _i < 6; ++_i)                                               \
      __builtin_amdgcn_global_load_lds(                                          \
          (const __attribute__((address_space(1))) void*)(_s + _i * 32),         \
          (__attribute__((address_space(3))) void*)(_d + _i * 1024), 16, 0, 0);  \
  } while (0)
#define STAGEV2(kt)                                                              \
  do {                                                                           \
    if (w == 0)                                                                  \
      __builtin_amdgcn_global_load_lds(                                          \
          (const __attribute__((address_space(1))) void*)(v2s + (kt) * 256),     \
          (__attribute__((address_space(3))) void*)((char*)lds + V2OFF + ((kt) & 1) * 256 + l * 4), \
          4, 0, 0);                                                              \
  } while (0)

  const float SC2 = 0.03608439182435161f * 1.44269504088896f;  // (1/sqrt(768))*log2e
  const float MB2 = 57.7078016355585f;                         // 40*log2e fixed max

  float ls = 0.f, c0 = 0.f, c1 = 0.f;    // per-lane: one q-row, half the keys

  STAGEH(0, 0, 0);
  STAGEV2(0);
  __syncthreads();

  f32x16 a0, a1;
  for (int kt = 0; kt < NKT; ++kt) {
    // ---- step A: compute dims 0..383 from buf0; stage dims 384..767 -> buf1
    STAGEH(1, kt, 1);
#pragma unroll
    for (int i = 0; i < 16; ++i) { a0[i] = 0.f; a1[i] = 0.f; }
    {
      const char* base = (const char*)lds + l * 16;
      __builtin_amdgcn_s_setprio(1);
#pragma unroll
      for (int i = 0; i < 24; ++i) {
        bf16x8 kf = *(const bf16x8*)(base + i * 1024);
        if (i & 1) a1 = __builtin_amdgcn_mfma_f32_32x32x16_bf16(kf, qf[i], a1, 0, 0, 0);
        else       a0 = __builtin_amdgcn_mfma_f32_32x32x16_bf16(kf, qf[i], a0, 0, 0, 0);
      }
      __builtin_amdgcn_s_setprio(0);
    }
    __syncthreads();

    // ---- step B: compute dims 384..767 from buf1; stage next tile half0 -> buf0
    if (kt + 1 < NKT) { STAGEH(0, kt + 1, 0); STAGEV2(kt + 1); }
    {
      const char* base = (const char*)lds + HFRB + l * 16;
      __builtin_amdgcn_s_setprio(1);
#pragma unroll
      for (int i = 0; i < 24; ++i) {
        bf16x8 kf = *(const bf16x8*)(base + i * 1024);
        if (i & 1) a1 = __builtin_amdgcn_mfma_f32_32x32x16_bf16(kf, qf[24 + i], a1, 0, 0, 0);
        else       a0 = __builtin_amdgcn_mfma_f32_32x32x16_bf16(kf, qf[24 + i], a0, 0, 0, 0);
      }
      __builtin_amdgcn_s_setprio(0);
    }
    // ---- softmax accumulate for tile kt (C: key=(r&3)+8*(r>>2)+4*hi, q-col=lo)
    {
      const char* vb = (const char*)lds + V2OFF + (kt & 1) * 256 + hi * 32;
#pragma unroll
      for (int rq = 0; rq < 4; ++rq) {
        f32x4 va = *(const f32x4*)(vb + rq * 64);        // keys 8rq+4hi, +1
        f32x4 vc = *(const f32x4*)(vb + rq * 64 + 16);   // keys 8rq+4hi+2, +3
#pragma unroll
        for (int j = 0; j < 4; ++j) {
          const float v0j = (j == 0) ? va[0] : (j == 1) ? va[2] : (j == 2) ? vc[0] : vc[2];
          const float v1j = (j == 0) ? va[1] : (j == 1) ? va[3] : (j == 2) ? vc[1] : vc[3];
          const int r = rq * 4 + j;
          const float p = exp2f(fmaf(a0[r] + a1[r], SC2, -MB2));
          ls += p; c0 = fmaf(p, v0j, c0); c1 = fmaf(p, v1j, c1);
        }
      }
    }
    __syncthreads();
  }
#undef STAGEH
#undef STAGEV2

  // fold the two hi-halves (same q-col, disjoint keys)
  ls += __shfl_xor(ls, 32); c0 += __shfl_xor(c0, 32); c1 += __shfl_xor(c1, 32);

  if (hi == 0) {
    float4* pp = (float4*)part + (size_t)ks * (BATCH * SEQ) + (size_t)b * SEQ;
    pp[q0 + lo] = make_float4(ls, c0, c1, 0.f);
  }
}

// ---------------- combine the 4 K-split partials + bias ----------------
__global__ __launch_bounds__(256)
void combine_kernel(const float* __restrict__ part, const float* __restrict__ bias,
                    float* __restrict__ out) {
  const int t = blockIdx.x * 256 + threadIdx.x;
  const float4* p4 = (const float4*)part;
  const float4 s0 = p4[t];
  const float4 s1 = p4[BATCH * SEQ + t];
  const float4 s2 = p4[2 * BATCH * SEQ + t];
  const float4 s3 = p4[3 * BATCH * SEQ + t];
  const float lsum = s0.x + s1.x + s2.x + s3.x;
  const float c0 = s0.y + s1.y + s2.y + s3.y;
  const float c1 = s0.z + s1.z + s2.z + s3.z;
  const float inv = 1.f / lsum;
  ((float2*)out)[t] = make_float2(c0 * inv + bias[0], c1 * inv + bias[1]);
}

extern "C" void kernel_launch(void* const* d_in, const int* in_sizes, int n_in,
                              void* d_out, int out_size, void* d_ws, size_t ws_size,
                              hipStream_t stream) {
  const float* x    = (const float*)d_in[0];
  const float* W    = (const float*)d_in[1];
  const float* bias = (const float*)d_in[2];
  float* out = (float*)d_out;

  __hip_bfloat16* xb = (__hip_bfloat16*)d_ws;                    // 25,165,824 B
  float* v2   = (float*)((char*)d_ws + 25165824);                //    131,072 B
  float* part = (float*)((char*)d_ws + 25165824 + 131072);       //  1,048,576 B

  prep_kernel<<<BATCH * SEQ / 4, 256, 0, stream>>>(x, W, xb, v2);
  attn_kernel<<<BATCH * KSPLIT * (SEQ / QBLK), 256, 0, stream>>>(xb, v2, part);
  combine_kernel<<<BATCH * SEQ / 256, 256, 0, stream>>>(part, bias, out);
}